// Round 1
// baseline (436.345 us; speedup 1.0000x reference)
//
#include <hip/hip_runtime.h>

#define N_NODES 50000
#define N_EDGES 800000
#define F_E     128
#define HID     256
#define F_OUT   128
#define DIN     256          // F_X + F_E
#define SCAN_BLOCKS ((N_NODES + 255) / 256)

// ---------------------------------------------------------------------------
// edge_index dtype detection: reference declares int64, but harness may pass
// int32. If int64 (little-endian, values < 50000 >= 0), every odd 32-bit word
// is zero. With int32 random values in [0,50000), P(256 odd words all 0) ~ 0.
// ---------------------------------------------------------------------------
__global__ __launch_bounds__(256) void detect_kernel(const unsigned int* ei_words, int* flag) {
    __shared__ int bad;
    if (threadIdx.x == 0) bad = 0;
    __syncthreads();
    unsigned int w = ei_words[2 * threadIdx.x + 1];
    if (w != 0u) atomicOr(&bad, 1);
    __syncthreads();
    if (threadIdx.x == 0) *flag = bad ? 0 : 1;   // 1 => int64
}

__device__ __forceinline__ int load_dst(const void* ei, int e, int is64) {
    if (is64) return (int)((const long long*)ei)[N_EDGES + e];
    return ((const int*)ei)[N_EDGES + e];
}

__global__ __launch_bounds__(256) void count_kernel(const void* ei, const int* flag, int* counts) {
    int e = blockIdx.x * 256 + threadIdx.x;
    if (e >= N_EDGES) return;
    int dst = load_dst(ei, e, *flag);
    atomicAdd(&counts[dst], 1);
}

__global__ __launch_bounds__(256) void scan1_kernel(const int* counts, int* blockSums) {
    __shared__ int s[256];
    int i = blockIdx.x * 256 + threadIdx.x;
    s[threadIdx.x] = (i < N_NODES) ? counts[i] : 0;
    __syncthreads();
    for (int off = 128; off > 0; off >>= 1) {
        if (threadIdx.x < off) s[threadIdx.x] += s[threadIdx.x + off];
        __syncthreads();
    }
    if (threadIdx.x == 0) blockSums[blockIdx.x] = s[0];
}

__global__ void scan2_kernel(const int* blockSums, int* blockOffs, int* offsets) {
    if (threadIdx.x == 0 && blockIdx.x == 0) {
        int acc = 0;
        for (int b = 0; b < SCAN_BLOCKS; b++) { blockOffs[b] = acc; acc += blockSums[b]; }
        offsets[N_NODES] = acc;   // == N_EDGES
    }
}

__global__ __launch_bounds__(256) void scan3_kernel(const int* counts, const int* blockOffs,
                                                    int* offsets, int* cursor) {
    __shared__ int s[256];
    int tid = threadIdx.x;
    int i = blockIdx.x * 256 + tid;
    int v = (i < N_NODES) ? counts[i] : 0;
    s[tid] = v;
    __syncthreads();
    for (int off = 1; off < 256; off <<= 1) {     // Hillis-Steele inclusive scan
        int t = (tid >= off) ? s[tid - off] : 0;
        __syncthreads();
        s[tid] += t;
        __syncthreads();
    }
    int excl = s[tid] - v + blockOffs[blockIdx.x];
    if (i < N_NODES) { offsets[i] = excl; cursor[i] = excl; }
}

__global__ __launch_bounds__(256) void fill_kernel(const void* ei, const int* flag,
                                                   int* cursor, int* edge_ids) {
    int e = blockIdx.x * 256 + threadIdx.x;
    if (e >= N_EDGES) return;
    int dst = load_dst(ei, e, *flag);
    int pos = atomicAdd(&cursor[dst], 1);
    edge_ids[pos] = e;
}

// one block per node; 128 threads = one feature each; coalesced 512B row reads
__global__ __launch_bounds__(128) void gather_kernel(const float* __restrict__ edge_attr,
                                                     const int* __restrict__ offsets,
                                                     const int* __restrict__ edge_ids,
                                                     float* __restrict__ agg) {
    int n = blockIdx.x;
    int f = threadIdx.x;
    int beg = offsets[n], end = offsets[n + 1];
    float acc = 0.0f;
    for (int p = beg; p < end; p++) {
        int eid = edge_ids[p];
        acc += edge_attr[eid * F_E + f];
    }
    int cnt = end - beg;
    agg[n * F_E + f] = acc / (float)(cnt > 0 ? cnt : 1);
}

// ---------------------------------------------------------------------------
// Fused MLP: out = relu([x|agg] @ W1 + b1) @ W2 + b2
// 256 threads, 32 nodes per block. One 32KB LDS buffer reused: inputs -> h.
// tx = tid&31 (owns 8 hid cols then 4 out cols), ty = tid>>5 (owns 4 nodes).
// ---------------------------------------------------------------------------
__global__ __launch_bounds__(256) void mlp_kernel(const float* __restrict__ x,
                                                  const float* __restrict__ agg,
                                                  const float* __restrict__ W1,
                                                  const float* __restrict__ b1,
                                                  const float* __restrict__ W2,
                                                  const float* __restrict__ b2,
                                                  float* __restrict__ out) {
    __shared__ float lds[32 * DIN];   // 32 KB, reused for node_inputs then h
    const int tid = threadIdx.x;
    const int base_node = blockIdx.x * 32;

    // stage node_inputs tile: [32][256] = concat(x_row, agg_row)
#pragma unroll
    for (int i = 0; i < 8; i++) {
        int idx = tid + 256 * i;        // 0..2047 float4 slots
        int row = idx >> 6;             // 0..31
        int q   = idx & 63;             // float4 within row
        int node = base_node + row;
        float4 v = make_float4(0.f, 0.f, 0.f, 0.f);
        if (node < N_NODES) {
            if (q < 32) v = *(const float4*)&x[node * 128 + q * 4];
            else        v = *(const float4*)&agg[node * 128 + (q - 32) * 4];
        }
        *(float4*)&lds[row * DIN + q * 4] = v;
    }
    __syncthreads();

    const int tx = tid & 31;
    const int ty = tid >> 5;

    // ---- phase 1: h[32][256], this thread: nodes ty*4+nn, hid cols tx*8+jj
    float acc[4][8];
#pragma unroll
    for (int nn = 0; nn < 4; nn++)
#pragma unroll
        for (int jj = 0; jj < 8; jj++) acc[nn][jj] = 0.f;

    for (int k4 = 0; k4 < DIN; k4 += 4) {
        float av[4][4];
#pragma unroll
        for (int nn = 0; nn < 4; nn++) {
            float4 t = *(const float4*)&lds[(ty * 4 + nn) * DIN + k4];
            av[nn][0] = t.x; av[nn][1] = t.y; av[nn][2] = t.z; av[nn][3] = t.w;
        }
#pragma unroll
        for (int kk = 0; kk < 4; kk++) {
            float4 w0 = *(const float4*)&W1[(k4 + kk) * HID + tx * 8];
            float4 w1 = *(const float4*)&W1[(k4 + kk) * HID + tx * 8 + 4];
            float wv[8] = {w0.x, w0.y, w0.z, w0.w, w1.x, w1.y, w1.z, w1.w};
#pragma unroll
            for (int nn = 0; nn < 4; nn++)
#pragma unroll
                for (int jj = 0; jj < 8; jj++)
                    acc[nn][jj] += av[nn][kk] * wv[jj];
        }
    }
    __syncthreads();   // everyone done reading inputs; reuse LDS for h

    {
        float4 bb0 = *(const float4*)&b1[tx * 8];
        float4 bb1 = *(const float4*)&b1[tx * 8 + 4];
        float bv[8] = {bb0.x, bb0.y, bb0.z, bb0.w, bb1.x, bb1.y, bb1.z, bb1.w};
#pragma unroll
        for (int nn = 0; nn < 4; nn++) {
            float h[8];
#pragma unroll
            for (int jj = 0; jj < 8; jj++) {
                float t = acc[nn][jj] + bv[jj];
                h[jj] = t > 0.f ? t : 0.f;
            }
            *(float4*)&lds[(ty * 4 + nn) * DIN + tx * 8]     = make_float4(h[0], h[1], h[2], h[3]);
            *(float4*)&lds[(ty * 4 + nn) * DIN + tx * 8 + 4] = make_float4(h[4], h[5], h[6], h[7]);
        }
    }
    __syncthreads();

    // ---- phase 2: out[32][128], this thread: nodes ty*4+nn, out cols tx*4+ff
    float acc2[4][4];
    {
        float4 bb = *(const float4*)&b2[tx * 4];
#pragma unroll
        for (int nn = 0; nn < 4; nn++) {
            acc2[nn][0] = bb.x; acc2[nn][1] = bb.y; acc2[nn][2] = bb.z; acc2[nn][3] = bb.w;
        }
    }
    for (int k4 = 0; k4 < HID; k4 += 4) {
        float av[4][4];
#pragma unroll
        for (int nn = 0; nn < 4; nn++) {
            float4 t = *(const float4*)&lds[(ty * 4 + nn) * DIN + k4];
            av[nn][0] = t.x; av[nn][1] = t.y; av[nn][2] = t.z; av[nn][3] = t.w;
        }
#pragma unroll
        for (int kk = 0; kk < 4; kk++) {
            float4 w = *(const float4*)&W2[(k4 + kk) * F_OUT + tx * 4];
            float wv[4] = {w.x, w.y, w.z, w.w};
#pragma unroll
            for (int nn = 0; nn < 4; nn++)
#pragma unroll
                for (int ff = 0; ff < 4; ff++)
                    acc2[nn][ff] += av[nn][kk] * wv[ff];
        }
    }

#pragma unroll
    for (int nn = 0; nn < 4; nn++) {
        int node = base_node + ty * 4 + nn;
        if (node < N_NODES)
            *(float4*)&out[node * F_OUT + tx * 4] =
                make_float4(acc2[nn][0], acc2[nn][1], acc2[nn][2], acc2[nn][3]);
    }
}

// ---------------------------------------------------------------------------
extern "C" void kernel_launch(void* const* d_in, const int* in_sizes, int n_in,
                              void* d_out, int out_size, void* d_ws, size_t ws_size,
                              hipStream_t stream) {
    const float* x         = (const float*)d_in[0];
    const void*  ei        = d_in[1];
    const float* edge_attr = (const float*)d_in[2];
    const float* W1        = (const float*)d_in[3];
    const float* b1        = (const float*)d_in[4];
    const float* W2        = (const float*)d_in[5];
    const float* b2        = (const float*)d_in[6];
    float* out = (float*)d_out;

    char* ws = (char*)d_ws;
    size_t off = 0;
    auto alloc = [&](size_t bytes) -> void* {
        void* p = ws + off;
        off = (off + bytes + 255) & ~(size_t)255;
        return p;
    };
    int*   flag      = (int*)alloc(4);
    int*   counts    = (int*)alloc((size_t)N_NODES * 4);
    int*   offsets   = (int*)alloc((size_t)(N_NODES + 1) * 4);
    int*   cursor    = (int*)alloc((size_t)N_NODES * 4);
    int*   blockSums = (int*)alloc((size_t)SCAN_BLOCKS * 4);
    int*   blockOffs = (int*)alloc((size_t)SCAN_BLOCKS * 4);
    int*   edge_ids  = (int*)alloc((size_t)N_EDGES * 4);
    float* agg       = (float*)alloc((size_t)N_NODES * F_E * 4);
    (void)ws_size; (void)in_sizes; (void)n_in; (void)out_size;

    hipMemsetAsync(counts, 0, (size_t)N_NODES * 4, stream);
    detect_kernel<<<1, 256, 0, stream>>>((const unsigned int*)ei, flag);
    count_kernel<<<(N_EDGES + 255) / 256, 256, 0, stream>>>(ei, flag, counts);
    scan1_kernel<<<SCAN_BLOCKS, 256, 0, stream>>>(counts, blockSums);
    scan2_kernel<<<1, 64, 0, stream>>>(blockSums, blockOffs, offsets);
    scan3_kernel<<<SCAN_BLOCKS, 256, 0, stream>>>(counts, blockOffs, offsets, cursor);
    fill_kernel<<<(N_EDGES + 255) / 256, 256, 0, stream>>>(ei, flag, cursor, edge_ids);
    gather_kernel<<<N_NODES, 128, 0, stream>>>(edge_attr, offsets, edge_ids, agg);
    mlp_kernel<<<(N_NODES + 31) / 32, 256, 0, stream>>>(x, agg, W1, b1, W2, b2, out);
}

// Round 2
// 311.416 us; speedup vs baseline: 1.4012x; 1.4012x over previous
//
#include <hip/hip_runtime.h>

#define N_NODES 50000
#define N_EDGES 800000
#define F_E     128
#define HID     256
#define F_OUT   128
#define DIN     256          // F_X + F_E
#define SCAN_BLOCKS ((N_NODES + 255) / 256)
#define LDA     264          // 256 + 8 bf16 pad (528B row stride -> 2-way bank alias, free)

typedef __attribute__((ext_vector_type(8))) short short8;   // 8 bf16 = 4 VGPR (MFMA A/B frag)
typedef __attribute__((ext_vector_type(4))) float f32x4;    // MFMA C/D frag

__device__ __forceinline__ short f2bf(float f) {            // fp32 -> bf16 RNE
    unsigned int u = __float_as_uint(f);
    u = u + 0x7FFFu + ((u >> 16) & 1u);
    return (short)(u >> 16);
}

// ---------------------------------------------------------------------------
// edge_index dtype detection (reference says int64; harness may deliver int32)
// ---------------------------------------------------------------------------
__global__ __launch_bounds__(256) void detect_kernel(const unsigned int* ei_words, int* flag) {
    __shared__ int bad;
    if (threadIdx.x == 0) bad = 0;
    __syncthreads();
    unsigned int w = ei_words[2 * threadIdx.x + 1];
    if (w != 0u) atomicOr(&bad, 1);
    __syncthreads();
    if (threadIdx.x == 0) *flag = bad ? 0 : 1;   // 1 => int64
}

__device__ __forceinline__ int load_dst(const void* ei, int e, int is64) {
    if (is64) return (int)((const long long*)ei)[N_EDGES + e];
    return ((const int*)ei)[N_EDGES + e];
}

__global__ __launch_bounds__(256) void count_kernel(const void* ei, const int* flag, int* counts) {
    int e = blockIdx.x * 256 + threadIdx.x;
    if (e >= N_EDGES) return;
    int dst = load_dst(ei, e, *flag);
    atomicAdd(&counts[dst], 1);
}

__global__ __launch_bounds__(256) void scan1_kernel(const int* counts, int* blockSums) {
    __shared__ int s[256];
    int i = blockIdx.x * 256 + threadIdx.x;
    s[threadIdx.x] = (i < N_NODES) ? counts[i] : 0;
    __syncthreads();
    for (int off = 128; off > 0; off >>= 1) {
        if (threadIdx.x < off) s[threadIdx.x] += s[threadIdx.x + off];
        __syncthreads();
    }
    if (threadIdx.x == 0) blockSums[blockIdx.x] = s[0];
}

__global__ void scan2_kernel(const int* blockSums, int* blockOffs, int* offsets) {
    if (threadIdx.x == 0 && blockIdx.x == 0) {
        int acc = 0;
        for (int b = 0; b < SCAN_BLOCKS; b++) { blockOffs[b] = acc; acc += blockSums[b]; }
        offsets[N_NODES] = acc;   // == N_EDGES
    }
}

__global__ __launch_bounds__(256) void scan3_kernel(const int* counts, const int* blockOffs,
                                                    int* offsets, int* cursor) {
    __shared__ int s[256];
    int tid = threadIdx.x;
    int i = blockIdx.x * 256 + tid;
    int v = (i < N_NODES) ? counts[i] : 0;
    s[tid] = v;
    __syncthreads();
    for (int off = 1; off < 256; off <<= 1) {
        int t = (tid >= off) ? s[tid - off] : 0;
        __syncthreads();
        s[tid] += t;
        __syncthreads();
    }
    int excl = s[tid] - v + blockOffs[blockIdx.x];
    if (i < N_NODES) { offsets[i] = excl; cursor[i] = excl; }
}

__global__ __launch_bounds__(256) void fill_kernel(const void* ei, const int* flag,
                                                   int* cursor, int* edge_ids) {
    int e = blockIdx.x * 256 + threadIdx.x;
    if (e >= N_EDGES) return;
    int dst = load_dst(ei, e, *flag);
    int pos = atomicAdd(&cursor[dst], 1);
    edge_ids[pos] = e;
}

// one block per node; 128 threads = one feature each; mean -> bf16
__global__ __launch_bounds__(128) void gather_kernel(const float* __restrict__ edge_attr,
                                                     const int* __restrict__ offsets,
                                                     const int* __restrict__ edge_ids,
                                                     unsigned short* __restrict__ agg16) {
    int n = blockIdx.x;
    int f = threadIdx.x;
    int beg = offsets[n], end = offsets[n + 1];
    float acc = 0.0f;
    for (int p = beg; p < end; p++) {
        int eid = edge_ids[p];
        acc += edge_attr[eid * F_E + f];
    }
    int cnt = end - beg;
    float mean = acc / (float)(cnt > 0 ? cnt : 1);
    agg16[n * F_E + f] = (unsigned short)f2bf(mean);
}

// ---------------------------------------------------------------------------
// Weight prep: W1[k][j] (256x256 f32) -> W1T[j][k] bf16 ; W2[k][j] (256x128) -> W2T[j][k] bf16
// ---------------------------------------------------------------------------
__global__ __launch_bounds__(256) void prep_w1t(const float* __restrict__ W1,
                                                unsigned short* __restrict__ W1T) {
    int idx = blockIdx.x * 256 + threadIdx.x;     // 65536
    int j = idx & 255, k = idx >> 8;              // coalesced read of W1 row k
    W1T[j * 256 + k] = (unsigned short)f2bf(W1[k * 256 + j]);
}
__global__ __launch_bounds__(256) void prep_w2t(const float* __restrict__ W2,
                                                unsigned short* __restrict__ W2T) {
    int idx = blockIdx.x * 256 + threadIdx.x;     // 32768
    int j = idx & 127, k = idx >> 7;
    W2T[j * 256 + k] = (unsigned short)f2bf(W2[k * 128 + j]);
}

// ---------------------------------------------------------------------------
// Fused bf16-MFMA MLP: out = relu([x|agg] @ W1 + b1) @ W2 + b2
// 256 thr = 4 waves, 64 nodes/block. A/H tile in LDS [64][264] bf16 (reused).
// Wave w: layer1 cols [w*64, w*64+64), layer2 cols [w*32, w*32+32).
// mfma_f32_16x16x32_bf16: A row=lane&15, k=(lane>>4)*8+j ; B col=lane&15 same k;
// C/D col=lane&15, row=(lane>>4)*4+reg  [verified layout].
// ---------------------------------------------------------------------------
__global__ __launch_bounds__(256) void mlp_mfma_kernel(const float* __restrict__ x,
                                                       const unsigned short* __restrict__ agg16,
                                                       const unsigned short* __restrict__ W1T,
                                                       const float* __restrict__ b1,
                                                       const unsigned short* __restrict__ W2T,
                                                       const float* __restrict__ b2,
                                                       float* __restrict__ out) {
    __shared__ short A_lds[64 * LDA];    // 33 KB, inputs then h
    const int tid  = threadIdx.x;
    const int base = blockIdx.x * 64;

    // ---- stage A = bf16(concat(x_row, agg_row)), zero for OOB nodes
    {
        const int nrow = tid >> 2;          // 0..63
        const int q    = tid & 3;           // 64-col quarter
        const int node = base + nrow;
        const int colbase = q * 64;
        if (q < 2) {
#pragma unroll
            for (int i = 0; i < 8; ++i) {
                short8 s = {};
                if (node < N_NODES) {
                    const float4 v0 = *(const float4*)&x[node * 128 + colbase + i * 8];
                    const float4 v1 = *(const float4*)&x[node * 128 + colbase + i * 8 + 4];
                    s[0] = f2bf(v0.x); s[1] = f2bf(v0.y); s[2] = f2bf(v0.z); s[3] = f2bf(v0.w);
                    s[4] = f2bf(v1.x); s[5] = f2bf(v1.y); s[6] = f2bf(v1.z); s[7] = f2bf(v1.w);
                }
                *(short8*)&A_lds[nrow * LDA + colbase + i * 8] = s;
            }
        } else {
            const int ab = (q - 2) * 64;
#pragma unroll
            for (int i = 0; i < 8; ++i) {
                short8 s = {};
                if (node < N_NODES)
                    s = *(const short8*)&agg16[node * 128 + ab + i * 8];
                *(short8*)&A_lds[nrow * LDA + 128 + ab + i * 8] = s;
            }
        }
    }
    __syncthreads();

    const int lane = tid & 63;
    const int wid  = tid >> 6;
    const int lr   = lane & 15;
    const int lg   = lane >> 4;
    const int wc   = wid * 64;

    // ---- layer 1: H[64][256] = relu(A @ W1 + b1), wave owns cols [wc, wc+64)
    f32x4 acc[4][4] = {};
#pragma unroll
    for (int kb = 0; kb < 8; ++kb) {
        short8 af[4];
#pragma unroll
        for (int m = 0; m < 4; ++m)
            af[m] = *(const short8*)&A_lds[(m * 16 + lr) * LDA + kb * 32 + lg * 8];
        short8 bf[4];
#pragma unroll
        for (int n = 0; n < 4; ++n)
            bf[n] = *(const short8*)&W1T[(wc + n * 16 + lr) * 256 + kb * 32 + lg * 8];
#pragma unroll
        for (int m = 0; m < 4; ++m)
#pragma unroll
            for (int n = 0; n < 4; ++n)
                acc[m][n] = __builtin_amdgcn_mfma_f32_16x16x32_bf16(af[m], bf[n], acc[m][n], 0, 0, 0);
    }

    float b1v[4];
#pragma unroll
    for (int n = 0; n < 4; ++n) b1v[n] = b1[wc + n * 16 + lr];

    __syncthreads();   // all waves done reading A; reuse buffer for H
#pragma unroll
    for (int m = 0; m < 4; ++m)
#pragma unroll
        for (int n = 0; n < 4; ++n)
#pragma unroll
            for (int i = 0; i < 4; ++i) {
                float h = acc[m][n][i] + b1v[n];
                h = h > 0.f ? h : 0.f;
                A_lds[(m * 16 + lg * 4 + i) * LDA + wc + n * 16 + lr] = f2bf(h);
            }
    __syncthreads();

    // ---- layer 2: out = H @ W2 + b2, wave owns cols [wid*32, wid*32+32)
    const int wc2 = wid * 32;
    f32x4 acc2[4][2] = {};
#pragma unroll
    for (int kb = 0; kb < 8; ++kb) {
        short8 af[4];
#pragma unroll
        for (int m = 0; m < 4; ++m)
            af[m] = *(const short8*)&A_lds[(m * 16 + lr) * LDA + kb * 32 + lg * 8];
        short8 bf[2];
#pragma unroll
        for (int n = 0; n < 2; ++n)
            bf[n] = *(const short8*)&W2T[(wc2 + n * 16 + lr) * 256 + kb * 32 + lg * 8];
#pragma unroll
        for (int m = 0; m < 4; ++m)
#pragma unroll
            for (int n = 0; n < 2; ++n)
                acc2[m][n] = __builtin_amdgcn_mfma_f32_16x16x32_bf16(af[m], bf[n], acc2[m][n], 0, 0, 0);
    }

    float b2v[2];
#pragma unroll
    for (int n = 0; n < 2; ++n) b2v[n] = b2[wc2 + n * 16 + lr];
#pragma unroll
    for (int m = 0; m < 4; ++m)
#pragma unroll
        for (int n = 0; n < 2; ++n)
#pragma unroll
            for (int i = 0; i < 4; ++i) {
                int node = base + m * 16 + lg * 4 + i;
                if (node < N_NODES)
                    out[node * F_OUT + wc2 + n * 16 + lr] = acc2[m][n][i] + b2v[n];
            }
}

// ---------------------------------------------------------------------------
extern "C" void kernel_launch(void* const* d_in, const int* in_sizes, int n_in,
                              void* d_out, int out_size, void* d_ws, size_t ws_size,
                              hipStream_t stream) {
    const float* x         = (const float*)d_in[0];
    const void*  ei        = d_in[1];
    const float* edge_attr = (const float*)d_in[2];
    const float* W1        = (const float*)d_in[3];
    const float* b1        = (const float*)d_in[4];
    const float* W2        = (const float*)d_in[5];
    const float* b2        = (const float*)d_in[6];
    float* out = (float*)d_out;

    char* ws = (char*)d_ws;
    size_t off = 0;
    auto alloc = [&](size_t bytes) -> void* {
        void* p = ws + off;
        off = (off + bytes + 255) & ~(size_t)255;
        return p;
    };
    int*            flag      = (int*)alloc(4);
    int*            counts    = (int*)alloc((size_t)N_NODES * 4);
    int*            offsets   = (int*)alloc((size_t)(N_NODES + 1) * 4);
    int*            cursor    = (int*)alloc((size_t)N_NODES * 4);
    int*            blockSums = (int*)alloc((size_t)SCAN_BLOCKS * 4);
    int*            blockOffs = (int*)alloc((size_t)SCAN_BLOCKS * 4);
    int*            edge_ids  = (int*)alloc((size_t)N_EDGES * 4);
    unsigned short* agg16     = (unsigned short*)alloc((size_t)N_NODES * F_E * 2);
    unsigned short* w1t       = (unsigned short*)alloc((size_t)DIN * HID * 2);
    unsigned short* w2t       = (unsigned short*)alloc((size_t)HID * F_OUT * 2);
    (void)ws_size; (void)in_sizes; (void)n_in; (void)out_size;

    hipMemsetAsync(counts, 0, (size_t)N_NODES * 4, stream);
    detect_kernel<<<1, 256, 0, stream>>>((const unsigned int*)ei, flag);
    prep_w1t<<<(DIN * HID) / 256, 256, 0, stream>>>(W1, w1t);
    prep_w2t<<<(HID * F_OUT) / 256, 256, 0, stream>>>(W2, w2t);
    count_kernel<<<(N_EDGES + 255) / 256, 256, 0, stream>>>(ei, flag, counts);
    scan1_kernel<<<SCAN_BLOCKS, 256, 0, stream>>>(counts, blockSums);
    scan2_kernel<<<1, 64, 0, stream>>>(blockSums, blockOffs, offsets);
    scan3_kernel<<<SCAN_BLOCKS, 256, 0, stream>>>(counts, blockOffs, offsets, cursor);
    fill_kernel<<<(N_EDGES + 255) / 256, 256, 0, stream>>>(ei, flag, cursor, edge_ids);
    gather_kernel<<<N_NODES, 128, 0, stream>>>(edge_attr, offsets, edge_ids, agg16);
    mlp_mfma_kernel<<<(N_NODES + 63) / 64, 256, 0, stream>>>(x, agg16, w1t, b1, w2t, b2, out);
}